// Round 18
// baseline (310.498 us; speedup 1.0000x reference)
//
#include <hip/hip_runtime.h>

typedef unsigned short u16;
typedef unsigned int u32;
typedef __attribute__((ext_vector_type(8))) __bf16 bf16x8;
typedef __attribute__((ext_vector_type(4))) float f32x4;
typedef __attribute__((ext_vector_type(4))) u32 u32x4;
typedef __attribute__((ext_vector_type(2))) u32 u32x2;
typedef __attribute__((ext_vector_type(8))) u16 u16x8;
typedef __attribute__((ext_vector_type(4))) u16 u16x4;

#define S_LEN 2048
#define DM 3072
#define NH 24
#define NKV 8

#define WAITV(n) asm volatile("s_waitcnt vmcnt(" #n ")" ::: "memory")

__device__ __forceinline__ u16 f2b(float f) {
  u32 u = __builtin_bit_cast(u32, f);
  u = u + 0x7FFFu + ((u >> 16) & 1u);
  return (u16)(u >> 16);
}
__device__ __forceinline__ float b2f(u16 h) {
  u32 u = ((u32)h) << 16;
  return __builtin_bit_cast(float, u);
}
__device__ __forceinline__ u32 cvtpk(float lo, float hi) {
  u32 r;
  asm("v_cvt_pk_bf16_f32 %0, %1, %2" : "=v"(r) : "v"(lo), "v"(hi));
  return r;
}
__device__ __forceinline__ f32x4 mfma16(bf16x8 a, bf16x8 b, f32x4 c) {
  return __builtin_amdgcn_mfma_f32_16x16x32_bf16(a, b, c, 0, 0, 0);
}
__device__ __forceinline__ void gload16(const u16* g, u16* l) {
  __builtin_amdgcn_global_load_lds((const __attribute__((address_space(1))) void*)g,
                                   (__attribute__((address_space(3))) void*)l, 16, 0, 0);
}

// ---------------- f32 -> bf16 conversion ----------------
__device__ __forceinline__ void cvt_one(const float* __restrict__ s, u16* __restrict__ d, int j) {
  const f32x4* p = (const f32x4*)(s + (size_t)j * 8);
  f32x4 a = p[0], b = p[1];
  u16x8 o;
#pragma unroll
  for (int q = 0; q < 4; ++q) { o[q] = f2b(a[q]); o[q + 4] = f2b(b[q]); }
  *(u16x8*)(d + (size_t)j * 8) = o;
}
__global__ __launch_bounds__(256) void cvt4_kernel(const float* __restrict__ s0, u16* __restrict__ d0,
                                                   const float* __restrict__ s1, u16* __restrict__ d1,
                                                   const float* __restrict__ s2, u16* __restrict__ d2,
                                                   const float* __restrict__ s3, u16* __restrict__ d3) {
  int i = blockIdx.x * 256 + threadIdx.x;
  if (i < 1572864)      cvt_one(s0, d0, i);
  else if (i < 2752512) cvt_one(s1, d1, i - 1572864);
  else if (i < 3145728) cvt_one(s2, d2, i - 2752512);
  else                  cvt_one(s3, d3, i - 3145728);
}

// ---------------- counted-vmcnt phase-interleaved GEMM (T4) ----------------
// C[m,n] = sum_k A[m,k]*B[n,k], row-major over K (K=3072, 48 K-tiles of 64).
// Variants: BM=256/BN=320 (NJ=5, qkv) and BM=128/BN=384 (NJ=6, O-proj).
// EVEN phases: each phase issues a uniform (MF/2) x NJ MFMA cluster.
// VISIBILITY RULE (r17 lesson): vmcnt is per-wave but slots are staged
// collectively -> any read of a slot must come AFTER an s_barrier that is
// preceded by every wave's counted wait covering that slot's loads. Hence
// bf[2..] reads sit after P0's post-WAITV barrier.
// modes: 0 bf16, 1 f32, 2 V^T bf16, 3 QKV-concat routing.
template <int BM, int BN>
__device__ __forceinline__ void gemm256_body(u16* __restrict__ lds,
                                             const u16* __restrict__ A, const u16* __restrict__ B,
                                             void* __restrict__ Cv, int N, int K,
                                             int m0, int n0, int mode,
                                             void* __restrict__ C2 = nullptr,
                                             void* __restrict__ C3 = nullptr) {
  constexpr int NJ = BN / 64;                  // B slots / per-wave n-frags (5 or 6)
  constexpr int NA = BM / 64;                  // A slots (4 or 2)
  constexpr int MF = BM / 32;                  // per-wave m-frags (8 or 4)
  constexpr int MH = MF / 2;                   // half m-frags per phase (4 or 2)
  constexpr int ABUF = BM * 64;                // A u16 per buffer
  constexpr int BBUF = NJ * 4096;              // B u16 per buffer
  const int tid = threadIdx.x;
  const int lane = tid & 63;
  const int w = tid >> 6;
  const int l15 = lane & 15, g = lane >> 4;
  const int wm = w >> 2, wn = w & 3;
  const int srow = tid >> 3;
  const int scol = ((tid & 7) ^ (srow & 7)) * 8;
  const u16* aS = A + (size_t)(m0 + srow) * K + scol;
  const u16* bS = B + (size_t)(n0 + srow) * K + scol;
  const int sdst = (tid & 448) * 8;
  const int swz0 = (g ^ (l15 & 7)) * 8;
  const int swz1 = ((4 + g) ^ (l15 & 7)) * 8;
  const int aB0 = wm * (BM * 32) + l15 * 64;
  const int bB0 = wn * 1024 + l15 * 64;        // within-slot row = wn*16 + l15

  f32x4 acc[MF][NJ];
#pragma unroll
  for (int i = 0; i < MF; ++i)
#pragma unroll
    for (int j = 0; j < NJ; ++j) acc[i][j] = 0.f;

  auto stgA = [&](int k0, int bsel) {
#pragma unroll
    for (int s = 0; s < NA; ++s)
      gload16(aS + (size_t)(s * 64) * K + k0, lds + bsel * ABUF + s * 4096 + sdst);
  };
  auto stgB = [&](int k0, int bsel, int s) {
    gload16(bS + (size_t)(s * 64) * K + k0, lds + 2 * ABUF + bsel * BBUF + s * 4096 + sdst);
  };

  // prologue: tile 0 (A slots, then B slots ascending); retire A+B01 before P0 reads
  stgA(0, 0);
#pragma unroll
  for (int s = 0; s < NJ; ++s) stgB(0, 0, s);
  if constexpr (BM == 256) WAITV(3); else WAITV(4);
  __builtin_amdgcn_s_barrier();

  for (int t = 0; t < 48; ++t) {
    const int bsel = t & 1, nsel = bsel ^ 1;
    const int kn = (t + 1) * 64;
    const bool st = (t < 47);
    const u16* ldsA = lds + bsel * ABUF + aB0;
    const u16* ldsB = lds + 2 * ABUF + bsel * BBUF + bB0;
    bf16x8 af[MH], bf[NJ];
    // ---- P0 (kh0, af-lo): read af-lo + b0,b1 | stgA(t+1) | counted wait | BARRIER |
    //      then read b2.. (slots globally visible only after the barrier)
#pragma unroll
    for (int mi = 0; mi < MH; ++mi) af[mi] = *(const bf16x8*)(ldsA + mi * 1024 + swz0);
    bf[0] = *(const bf16x8*)(ldsB + swz0);
    bf[1] = *(const bf16x8*)(ldsB + 4096 + swz0);
    if (st) stgA(kn, nsel);
    asm volatile("" ::: "memory");
    if (st) { if constexpr (BM == 256) WAITV(4); else WAITV(2); }
    else WAITV(0);
    __builtin_amdgcn_s_barrier();
#pragma unroll
    for (int j = 2; j < NJ; ++j) bf[j] = *(const bf16x8*)(ldsB + j * 4096 + swz0);
    __builtin_amdgcn_s_setprio(1);
#pragma unroll
    for (int mi = 0; mi < MH; ++mi)
#pragma unroll
      for (int j = 0; j < NJ; ++j) acc[mi][j] = mfma16(af[mi], bf[j], acc[mi][j]);
    __builtin_amdgcn_s_setprio(0);
    asm volatile("" ::: "memory");
    __builtin_amdgcn_s_barrier();
    // ---- P1 (kh0, af-hi): read af-hi | stage B slots
#pragma unroll
    for (int mi = 0; mi < MH; ++mi) af[mi] = *(const bf16x8*)(ldsA + (MH + mi) * 1024 + swz0);
    if (st) {
      stgB(kn, nsel, 0); stgB(kn, nsel, 1);
      if constexpr (BM == 128) stgB(kn, nsel, 2);
    }
    asm volatile("" ::: "memory");
    __builtin_amdgcn_s_barrier();
    __builtin_amdgcn_s_setprio(1);
#pragma unroll
    for (int mi = 0; mi < MH; ++mi)
#pragma unroll
      for (int j = 0; j < NJ; ++j) acc[MH + mi][j] = mfma16(af[mi], bf[j], acc[MH + mi][j]);
    __builtin_amdgcn_s_setprio(0);
    asm volatile("" ::: "memory");
    __builtin_amdgcn_s_barrier();
    // ---- P2 (kh1, af-lo): read af-lo + all b kh1 (tile-t fully visible since P0's
    //      barrier) | stage B slots
#pragma unroll
    for (int mi = 0; mi < MH; ++mi) af[mi] = *(const bf16x8*)(ldsA + mi * 1024 + swz1);
#pragma unroll
    for (int j = 0; j < NJ; ++j) bf[j] = *(const bf16x8*)(ldsB + j * 4096 + swz1);
    if (st) {
      if constexpr (BM == 256) { stgB(kn, nsel, 2); stgB(kn, nsel, 3); }
      else { stgB(kn, nsel, 3); stgB(kn, nsel, 4); stgB(kn, nsel, 5); }
    }
    asm volatile("" ::: "memory");
    __builtin_amdgcn_s_barrier();
    __builtin_amdgcn_s_setprio(1);
#pragma unroll
    for (int mi = 0; mi < MH; ++mi)
#pragma unroll
      for (int j = 0; j < NJ; ++j) acc[mi][j] = mfma16(af[mi], bf[j], acc[mi][j]);
    __builtin_amdgcn_s_setprio(0);
    asm volatile("" ::: "memory");
    __builtin_amdgcn_s_barrier();
    // ---- P3 (kh1, af-hi): read af-hi | stage last B | counted wait [A+B01 of t+1]
#pragma unroll
    for (int mi = 0; mi < MH; ++mi) af[mi] = *(const bf16x8*)(ldsA + (MH + mi) * 1024 + swz1);
    if (st) {
      if constexpr (BM == 256) stgB(kn, nsel, 4);
      asm volatile("" ::: "memory");
      if constexpr (BM == 256) WAITV(3); else WAITV(4);
    }
    __builtin_amdgcn_s_barrier();
    __builtin_amdgcn_s_setprio(1);
#pragma unroll
    for (int mi = 0; mi < MH; ++mi)
#pragma unroll
      for (int j = 0; j < NJ; ++j) acc[MH + mi][j] = mfma16(af[mi], bf[j], acc[MH + mi][j]);
    __builtin_amdgcn_s_setprio(0);
    asm volatile("" ::: "memory");
    __builtin_amdgcn_s_barrier();
  }
  // ---- epilogue (nn = n0 + j*64 + wn*16 + l15)
#pragma unroll
  for (int i = 0; i < MF; ++i)
#pragma unroll
    for (int j = 0; j < NJ; ++j) {
      int nn = n0 + j * 64 + wn * 16 + l15;
      int mmb = m0 + wm * (BM / 2) + i * 16 + g * 4;
      if (mode == 1) {
#pragma unroll
        for (int r = 0; r < 4; ++r)
          ((float*)Cv)[(size_t)(mmb + r) * N + nn] = acc[i][j][r];
      } else if (mode == 0) {
#pragma unroll
        for (int r = 0; r < 4; ++r)
          ((u16*)Cv)[(size_t)(mmb + r) * N + nn] = f2b(acc[i][j][r]);
      } else if (mode == 2) {
        u16x4 pk;
#pragma unroll
        for (int r = 0; r < 4; ++r) pk[r] = f2b(acc[i][j][r]);
        *(u16x4*)((u16*)Cv + (size_t)nn * 2048 + (size_t)(mmb >> 11) * 2097152 + (mmb & 2047)) = pk;
      } else {                                 // mode 3: QKV concat routing
        if (nn < 3072) {
#pragma unroll
          for (int r = 0; r < 4; ++r)
            ((u16*)Cv)[(size_t)(mmb + r) * 3072 + nn] = f2b(acc[i][j][r]);
        } else if (nn < 4096) {
#pragma unroll
          for (int r = 0; r < 4; ++r)
            ((u16*)C2)[(size_t)(mmb + r) * 1024 + (nn - 3072)] = f2b(acc[i][j][r]);
        } else {
          int d = nn - 4096;
          u16x4 pk;
#pragma unroll
          for (int r = 0; r < 4; ++r) pk[r] = f2b(acc[i][j][r]);
          *(u16x4*)((u16*)C3 + (size_t)d * 2048 + (size_t)(mmb >> 11) * 2097152 + (mmb & 2047)) = pk;
        }
      }
    }
}

// merged QKV projection: B = concatenated [wq;wk;wv] (5120x3072, contiguous in ws).
// grid 256 = 16 row-panels x 16 col-tiles of 320 -> one full machine round.
__global__ __launch_bounds__(512, 1) void gemm_qkv(const u16* __restrict__ A,
                                                   const u16* __restrict__ Wcat,
                                                   u16* __restrict__ Cq,
                                                   u16* __restrict__ Ck, u16* __restrict__ Cv,
                                                   int K) {
  __shared__ __align__(16) u16 lds[73728];     // 144 KB
  int id = blockIdx.x;
  int s = (id & 7) * 32 + (id >> 3);           // XCD-chunked (A-panel locality)
  int by = s >> 4, c = s & 15;
  gemm256_body<256, 320>(lds, A, Wcat, Cq, 0, K, by * 256, c * 320, 3, Ck, Cv);
}
// O-projection (f32 out): BM=128 x BN=384, grid 256 = 32 row x 8 col -> one round.
__global__ __launch_bounds__(512, 1) void gemm384_f32(const u16* __restrict__ A, const u16* __restrict__ B,
                                                      float* __restrict__ C, int N, int K) {
  __shared__ __align__(16) u16 lds[65536];     // 128 KB
  int id = blockIdx.x;
  int s = (id & 7) * 32 + (id >> 3);           // XCD-chunked
  int by = s >> 3, c = s & 7;
  gemm256_body<128, 384>(lds, A, B, C, N, K, by * 128, c * 384, 1);
}

// ---------------- RoPE (in place, bf16) — K only ----------------
__global__ __launch_bounds__(256) void rope_kernel(u16* __restrict__ t, const float* __restrict__ fc,
                                                   const float* __restrict__ fs, int nheads, int total) {
  int idx = blockIdx.x * 256 + threadIdx.x;
  if (idx >= total) return;
  int c = idx & 7;
  int tmp = idx >> 3;
  int h = tmp % nheads;
  int row = tmp / nheads;
  int s = row & (S_LEN - 1);
  int d0 = c << 3;
  u16* base = t + (size_t)row * (nheads * 128) + h * 128;
  u16x8 lo = *(const u16x8*)(base + d0);
  u16x8 hi = *(const u16x8*)(base + 64 + d0);
  const float* cp = fc + s * 64 + d0;
  const float* sp = fs + s * 64 + d0;
  u16x8 olo, ohi;
#pragma unroll
  for (int j = 0; j < 8; ++j) {
    float cv = cp[j], sn = sp[j];
    float a = b2f(lo[j]), b = b2f(hi[j]);
    olo[j] = f2b(a * cv - b * sn);
    ohi[j] = f2b(b * cv + a * sn);
  }
  *(u16x8*)(base + d0) = olo;
  *(u16x8*)(base + 64 + d0) = ohi;
}

// ---------------- causal GQA flash attention — single-panel LPT blocks (r15) ----------------
__global__ __launch_bounds__(256, 2) void attn_kernel(const u16* __restrict__ xq,
                                                      const u16* __restrict__ xk,
                                                      const u16* __restrict__ xvT,
                                                      const float* __restrict__ fc,
                                                      const float* __restrict__ fs,
                                                      u16* __restrict__ o,
                                                      const float* __restrict__ wo,
                                                      u16* __restrict__ wob) {
  __shared__ __align__(16) u16 smem[40960];    // 80 KB: K dbuf 32K + V dbuf 32K + P 16K
  if (blockIdx.x >= 768) {                     // cvt(wo) backfill blocks
    int i = (blockIdx.x - 768) * 256 + threadIdx.x;   // 4608*256 = 1179648 exactly
    cvt_one(wo, wob, i);
    return;
  }
  const int tid = threadIdx.x;
  const int w = tid >> 6, lane = tid & 63;
  const int l15 = lane & 15, g = lane >> 4;
  const int id = blockIdx.x;
  const int xcd = id & 7, slot = id >> 3;      // slot in [0,96)
  const int grp = xcd + 8 * (slot / 48);       // (b,kvh) group, 0..15
  const int s48 = slot % 48;
  const int b = grp >> 3, kvh = grp & 7;
  const int qb = 15 - s48 / 3;                 // qb descending (LPT)
  const int h = kvh * 3 + s48 % 3;
  const float sc2 = 0.08838834764831845f * 1.4426950408889634f;  // 1/sqrt(128)*log2e

  const u16* ksrc = xk + (size_t)b * 2097152 + kvh * 128;          // [s][1024]
  const u16* vsrc = xvT + (size_t)(b * 1024 + kvh * 128) * 2048;   // [d][2048]
  int koff[4], vofs[4], dst4[4];
#pragma unroll
  for (int r = 0; r < 4; ++r) {
    int c = r * 256 + tid;
    int krow = c >> 4, kj = (c & 15) ^ (krow & 7);   // K: 64 rows x 16 chunks
    koff[r] = krow * 1024 + kj * 8;
    int vrow = c >> 3, vj = (c & 7) ^ (vrow & 7);    // V^T: 128 rows x 8 chunks
    vofs[r] = vrow * 2048 + vj * 8;
    dst4[r] = (r * 256 + (tid & 192)) * 8;           // wave-uniform LDS chunk base
  }
  u16* sPw = smem + 32768 + w * 2048;          // per-wave P: 2 sets x 1024 u16
  const int pxr = (l15 & 7) << 3;

  const int q0 = qb * 128;

  // Q load + fused RoPE + pre-scale, 2 sets
  bf16x8 qf[2][4];
#pragma unroll
  for (int s = 0; s < 2; ++s) {
    const int qrow = q0 + w * 32 + s * 16 + l15;
    const u16* qptr = xq + (size_t)(b * S_LEN + qrow) * DM + h * 128;
#pragma unroll
    for (int dcp = 0; dcp < 2; ++dcp) {
      u16x8 Lo = *(const u16x8*)(qptr + dcp * 32 + g * 8);
      u16x8 Hi = *(const u16x8*)(qptr + 64 + dcp * 32 + g * 8);
      const float* cp = fc + qrow * 64 + dcp * 32 + g * 8;
      const float* sp = fs + qrow * 64 + dcp * 32 + g * 8;
      bf16x8 qlo, qhi;
#pragma unroll
      for (int j = 0; j < 8; ++j) {
        float cv = cp[j], sn = sp[j];
        float a = b2f(Lo[j]), bb = b2f(Hi[j]);
        qlo[j] = (__bf16)((a * cv - bb * sn) * sc2);
        qhi[j] = (__bf16)((bb * cv + a * sn) * sc2);
      }
      qf[s][dcp] = qlo;
      qf[s][dcp + 2] = qhi;
    }
  }

  u16 *sKc = smem, *sKn = smem + 8192;
  u16 *sVc = smem + 16384, *sVn = smem + 24576;

  f32x4 accO[2][8];
#pragma unroll
  for (int s = 0; s < 2; ++s)
#pragma unroll
    for (int i = 0; i < 8; ++i) accO[s][i] = 0.f;
  float m_[2] = {-1e30f, -1e30f}, ls_[2] = {0.f, 0.f};
  const int nt = 2 * qb + 2;

#pragma unroll
  for (int r = 0; r < 4; ++r) gload16(ksrc + koff[r], sKc + dst4[r]);
#pragma unroll
  for (int r = 0; r < 4; ++r) gload16(vsrc + vofs[r], sVc + dst4[r]);
  __syncthreads();

  for (int t = 0; t < nt; ++t) {
    if (t + 1 < nt) {
      int k0n = (t + 1) * 64;
#pragma unroll
      for (int r = 0; r < 4; ++r) gload16(ksrc + (size_t)k0n * 1024 + koff[r], sKn + dst4[r]);
#pragma unroll
      for (int r = 0; r < 4; ++r) gload16(vsrc + k0n + vofs[r], sVn + dst4[r]);
    }
    if (64 * t <= q0 + w * 32 + 31) {           // wave-level causal skip
      f32x4 st[2][4];
      __builtin_amdgcn_s_setprio(1);
#pragma unroll
      for (int kt = 0; kt < 4; ++kt) {
        int row = kt * 16 + l15;
        bf16x8 kf[4];
#pragma unroll
        for (int dc = 0; dc < 4; ++dc)
          kf[dc] = *(const bf16x8*)(sKc + row * 128 + ((dc * 32 + g * 8) ^ ((row & 7) << 3)));
        f32x4 a0 = 0.f, a1 = 0.f;
#pragma unroll
        for (int dc = 0; dc < 4; ++dc) {
          a0 = mfma16(kf[dc], qf[0][dc], a0);
          a1 = mfma16(kf[dc], qf[1][dc], a1);
        }
        st[0][kt] = a0;
        st[1][kt] = a1;
      }
      __builtin_amdgcn_s_setprio(0);
      // softmax per set: mask, tree-max, defer-max, exp2, cvtpk pack, partial lsum
#pragma unroll
      for (int s = 0; s < 2; ++s) {
        const int qrow = q0 + w * 32 + s * 16 + l15;
#pragma unroll
        for (int kt = 0; kt < 4; ++kt)
#pragma unroll
          for (int r = 0; r < 4; ++r) {
            float x = st[s][kt][r];
            if (t >= nt - 2) {
              int kk = t * 64 + kt * 16 + g * 4 + r;
              if (kk > qrow) x = -1e30f;
            }
            st[s][kt][r] = x;
          }
        float pm0 = fmaxf(fmaxf(st[s][0][0], st[s][0][1]), fmaxf(st[s][0][2], st[s][0][3]));
        float pm1 = fmaxf(fmaxf(st[s][1][0], st[s][1][1]), fmaxf(st[s][1][2], st[s][1][3]));
        float pm2 = fmaxf(fmaxf(st[s][2][0], st[s][2][1]), fmaxf(st[s][2][2], st[s][2][3]));
        float pm3 = fmaxf(fmaxf(st[s][3][0], st[s][3][1]), fmaxf(st[s][3][2], st[s][3][3]));
        float pmax = fmaxf(fmaxf(pm0, pm1), fmaxf(pm2, pm3));
        pmax = fmaxf(pmax, __shfl_xor(pmax, 16));
        pmax = fmaxf(pmax, __shfl_xor(pmax, 32));
        if (!__all(pmax - m_[s] <= 8.0f)) {    // defer-max
          float mnew = fmaxf(m_[s], pmax);
          float corr = exp2f(m_[s] - mnew);
          ls_[s] *= corr;
#pragma unroll
          for (int i = 0; i < 8; ++i) accO[s][i] *= corr;
          m_[s] = mnew;
        }
        float ps = 0.f;
#pragma unroll
        for (int kt = 0; kt < 4; ++kt) {
          float p0 = exp2f(st[s][kt][0] - m_[s]);
          float p1 = exp2f(st[s][kt][1] - m_[s]);
          float p2 = exp2f(st[s][kt][2] - m_[s]);
          float p3 = exp2f(st[s][kt][3] - m_[s]);
          ps += (p0 + p1) + (p2 + p3);
          u32x2 pr;
          pr[0] = cvtpk(p0, p1);
          pr[1] = cvtpk(p2, p3);
          *(u32x2*)(sPw + s * 1024 + ((l15 * 64 + kt * 16 + g * 4) ^ pxr)) = pr;
        }
        ls_[s] += ps;                          // per-lane partial; reduce at epilogue
      }
      // P fragments (wave-local LDS)
      bf16x8 pf[2][2];
#pragma unroll
      for (int s = 0; s < 2; ++s)
#pragma unroll
        for (int ck = 0; ck < 2; ++ck)
          pf[s][ck] = *(const bf16x8*)(sPw + s * 1024 + ((l15 * 64 + ck * 32 + g * 8) ^ pxr));
      // PV both sets: each vf read feeds 2 MFMAs
      __builtin_amdgcn_s_setprio(1);
#pragma unroll
      for (int dt = 0; dt < 8; ++dt) {
        int row = dt * 16 + l15;
#pragma unroll
        for (int ck = 0; ck < 2; ++ck) {
          bf16x8 vf = *(const bf16x8*)(sVc + row * 64 + ((ck * 32 + g * 8) ^ ((row & 7) << 3)));
          accO[0][dt] = mfma16(vf, pf[0][ck], accO[0][dt]);
          accO[1][dt] = mfma16(vf, pf[1][ck], accO[1][dt]);
        }
      }
      __builtin_amdgcn_s_setprio(0);
    }
    __syncthreads();                            // drains stage vmcnt + cur reads done
    u16* tk = sKc; sKc = sKn; sKn = tk;
    u16* tv = sVc; sVc = sVn; sVn = tv;
  }
  // cross-lane lsum reduce (deferred from the k-loop)
#pragma unroll
  for (int s = 0; s < 2; ++s) {
    ls_[s] += __shfl_xor(ls_[s], 16);
    ls_[s] += __shfl_xor(ls_[s], 32);
  }
  // epilogue: per-wave [32 q][128 d] transpose in (dead) K/V LDS region
  u16* sOw = smem + w * 8192;
#pragma unroll
  for (int s = 0; s < 2; ++s) {
    float invl = 1.0f / ls_[s];
#pragma unroll
    for (int dt = 0; dt < 8; ++dt) {
      u32x2 pr;
      pr[0] = cvtpk(accO[s][dt][0] * invl, accO[s][dt][1] * invl);
      pr[1] = cvtpk(accO[s][dt][2] * invl, accO[s][dt][3] * invl);
      int d = dt * 16 + g * 4;
      *(u32x2*)(sOw + (((s * 16 + l15) * 128 + d) ^ pxr)) = pr;
    }
  }
#pragma unroll
  for (int p = 0; p < 8; ++p) {
    int idx = p * 64 + lane;
    int q = idx >> 4, c = idx & 15;
    int j = c ^ (q & 7);
    u32x4 v = *(const u32x4*)(sOw + q * 128 + j * 8);
    *(u32x4*)(o + (size_t)(b * S_LEN + q0 + w * 32 + q) * DM + h * 128 + c * 8) = v;
  }
}

// ---------------- launch ----------------
extern "C" void kernel_launch(void* const* d_in, const int* in_sizes, int n_in,
                              void* d_out, int out_size, void* d_ws, size_t ws_size,
                              hipStream_t stream) {
  const float* x  = (const float*)d_in[0];
  const float* fc = (const float*)d_in[1];
  const float* fs = (const float*)d_in[2];
  const float* wq = (const float*)d_in[4];
  const float* wk = (const float*)d_in[5];
  const float* wv = (const float*)d_in[6];
  const float* wo = (const float*)d_in[7];
  float* out = (float*)d_out;
  char* ws = (char*)d_ws;

  u16* xb  = (u16*)(ws);                 // x bf16      25,165,824
  u16* wqb = (u16*)(ws + 25165824);      // wq bf16     18,874,368 ┐ contiguous = Wcat
  u16* att = (u16*)(ws + 25165824);      // attn out (aliases wq/wk after death)
  u16* wkb = (u16*)(ws + 44040192);      // wk bf16      6,291,456 │ (5120 x 3072)
  u16* wvb = (u16*)(ws + 50331648);      // wv bf16      6,291,456 ┘
  u16* xqb = (u16*)(ws + 56623104);      // xq bf16     25,165,824
  u16* xkb = (u16*)(ws + 81788928);      // xk bf16      8,388,608
  u16* xvT = (u16*)(ws + 90177536);      // V^T bf16     8,388,608
  u16* wob = (u16*)(ws);                 // wo bf16 (aliases xb, dead after gemm_qkv)

  cvt4_kernel<<<13824, 256, 0, stream>>>(x, xb, wq, wqb, wk, wkb, wv, wvb);

  gemm_qkv<<<256, 512, 0, stream>>>(xb, wqb, xqb, xkb, xvT, 3072);

  rope_kernel<<<1024, 256, 0, stream>>>(xkb, fc, fs, NKV, 4096 * NKV * 8);  // K only

  attn_kernel<<<5376, 256, 0, stream>>>(xqb, xkb, xvT, fc, fs, att, wo, wob);

  gemm384_f32<<<256, 512, 0, stream>>>(att, wob, out, 3072, 3072);
}

// Round 19
// 308.424 us; speedup vs baseline: 1.0067x; 1.0067x over previous
//
#include <hip/hip_runtime.h>

typedef unsigned short u16;
typedef unsigned int u32;
typedef __attribute__((ext_vector_type(8))) __bf16 bf16x8;
typedef __attribute__((ext_vector_type(4))) float f32x4;
typedef __attribute__((ext_vector_type(4))) u32 u32x4;
typedef __attribute__((ext_vector_type(2))) u32 u32x2;
typedef __attribute__((ext_vector_type(8))) u16 u16x8;
typedef __attribute__((ext_vector_type(4))) u16 u16x4;

#define S_LEN 2048
#define DM 3072
#define NH 24
#define NKV 8

#define WAITV(n) asm volatile("s_waitcnt vmcnt(" #n ")" ::: "memory")

__device__ __forceinline__ u16 f2b(float f) {
  u32 u = __builtin_bit_cast(u32, f);
  u = u + 0x7FFFu + ((u >> 16) & 1u);
  return (u16)(u >> 16);
}
__device__ __forceinline__ float b2f(u16 h) {
  u32 u = ((u32)h) << 16;
  return __builtin_bit_cast(float, u);
}
__device__ __forceinline__ u32 cvtpk(float lo, float hi) {
  u32 r;
  asm("v_cvt_pk_bf16_f32 %0, %1, %2" : "=v"(r) : "v"(lo), "v"(hi));
  return r;
}
__device__ __forceinline__ f32x4 mfma16(bf16x8 a, bf16x8 b, f32x4 c) {
  return __builtin_amdgcn_mfma_f32_16x16x32_bf16(a, b, c, 0, 0, 0);
}
__device__ __forceinline__ void gload16(const u16* g, u16* l) {
  __builtin_amdgcn_global_load_lds((const __attribute__((address_space(1))) void*)g,
                                   (__attribute__((address_space(3))) void*)l, 16, 0, 0);
}

// ---------------- f32 -> bf16 conversion ----------------
__device__ __forceinline__ void cvt_one(const float* __restrict__ s, u16* __restrict__ d, int j) {
  const f32x4* p = (const f32x4*)(s + (size_t)j * 8);
  f32x4 a = p[0], b = p[1];
  u16x8 o;
#pragma unroll
  for (int q = 0; q < 4; ++q) { o[q] = f2b(a[q]); o[q + 4] = f2b(b[q]); }
  *(u16x8*)(d + (size_t)j * 8) = o;
}
__global__ __launch_bounds__(256) void cvt4_kernel(const float* __restrict__ s0, u16* __restrict__ d0,
                                                   const float* __restrict__ s1, u16* __restrict__ d1,
                                                   const float* __restrict__ s2, u16* __restrict__ d2,
                                                   const float* __restrict__ s3, u16* __restrict__ d3) {
  int i = blockIdx.x * 256 + threadIdx.x;
  if (i < 1572864)      cvt_one(s0, d0, i);
  else if (i < 2752512) cvt_one(s1, d1, i - 1572864);
  else if (i < 3145728) cvt_one(s2, d2, i - 2752512);
  else                  cvt_one(s3, d3, i - 3145728);
}

// ---------------- XCD-aware block swizzle ----------------
__device__ __forceinline__ void swz_bid(int& bx, int& by) {
  int gx = gridDim.x;
  int tot = gx * gridDim.y;          // must be divisible by 8
  int id = blockIdx.y * gx + blockIdx.x;
  int cpx = tot >> 3;
  int s = (id & 7) * cpx + (id >> 3);
  bx = s % gx;
  by = s / gx;
}

// ---------------- counted-vmcnt phase-interleaved GEMM (T4, r14/r15-proven) ----------------
// C[m,n] = sum_k A[m,k]*B[n,k], row-major over K (K = 3072, 48 K-tiles of 64).
// BM=256, BN in {320,192}; 512 threads = 8 waves (2M x 4N). bf[j] slot-aligned:
// rows j*64 + wn*16 + l15. Staggered staging (P0:A, P1:B01, P2:B23, P3:B4) +
// counted waits vmcnt(4)@P0 / vmcnt(NJ-2)@P3 — loads stay in flight across
// barriers (never drain to 0 in steady state). All late-slot reads sit after
// barriers that are preceded by every wave's covering counted wait (r17 rule).
// modes: 0 bf16, 1 f32, 2 V^T bf16, 3 QKV-concat routing.
template <int BN>
__device__ __forceinline__ void gemm256_body(u16* __restrict__ lds,
                                             const u16* __restrict__ A, const u16* __restrict__ B,
                                             void* __restrict__ Cv, int N, int K,
                                             int m0, int n0, int mode,
                                             void* __restrict__ C2 = nullptr,
                                             void* __restrict__ C3 = nullptr) {
  constexpr int NJ = BN / 64;                  // B slots / per-wave n-frags (5 or 3)
  constexpr int BBUF = NJ * 4096;              // B u16 per buffer
  const int tid = threadIdx.x;
  const int lane = tid & 63;
  const int w = tid >> 6;
  const int l15 = lane & 15, g = lane >> 4;
  const int wm = w >> 2, wn = w & 3;
  const int srow = tid >> 3;
  const int scol = ((tid & 7) ^ (srow & 7)) * 8;
  const u16* aS = A + (size_t)(m0 + srow) * K + scol;
  const u16* bS = B + (size_t)(n0 + srow) * K + scol;
  const int sdst = (tid & 448) * 8;
  const int swz0 = (g ^ (l15 & 7)) * 8;
  const int swz1 = ((4 + g) ^ (l15 & 7)) * 8;
  const int aB0 = wm * 8192 + l15 * 64;
  const int bB0 = wn * 1024 + l15 * 64;        // within-slot row = wn*16 + l15

  f32x4 acc[8][NJ];
#pragma unroll
  for (int i = 0; i < 8; ++i)
#pragma unroll
    for (int j = 0; j < NJ; ++j) acc[i][j] = 0.f;

  auto stgA = [&](int k0, int bsel) {
#pragma unroll
    for (int s = 0; s < 4; ++s)
      gload16(aS + (size_t)(s * 64) * K + k0, lds + bsel * 16384 + s * 4096 + sdst);
  };
  auto stgB = [&](int k0, int bsel, int s) {
    gload16(bS + (size_t)(s * 64) * K + k0, lds + 32768 + bsel * BBUF + s * 4096 + sdst);
  };

  // prologue: tile 0 (A, then B slots ascending), retire A+B01 before first reads
  stgA(0, 0);
#pragma unroll
  for (int s = 0; s < NJ; ++s) stgB(0, 0, s);
  if constexpr (NJ == 5) WAITV(3); else WAITV(1);
  __builtin_amdgcn_s_barrier();

  for (int t = 0; t < 48; ++t) {
    const int bsel = t & 1, nsel = bsel ^ 1;
    const int kn = (t + 1) * 64;
    const bool st = (t < 47);
    const u16* ldsA = lds + bsel * 16384 + aB0;
    const u16* ldsB = lds + 32768 + bsel * BBUF + bB0;
    bf16x8 af[8], b0, b1, bx[NJ - 2];
    // ---- P0: read af kh0 + bf{0,1} kh0 | stage A(t+1) | vmcnt(4) [B23,B4 of t land]
#pragma unroll
    for (int mi = 0; mi < 8; ++mi) af[mi] = *(const bf16x8*)(ldsA + mi * 1024 + swz0);
    b0 = *(const bf16x8*)(ldsB + swz0);
    b1 = *(const bf16x8*)(ldsB + 4096 + swz0);
    if (st) stgA(kn, nsel);
    asm volatile("" ::: "memory");
    if (st) WAITV(4); else WAITV(0);
    __builtin_amdgcn_s_barrier();
    asm volatile("s_waitcnt lgkmcnt(0)" ::: "memory");
    __builtin_amdgcn_sched_barrier(0);
    __builtin_amdgcn_s_setprio(1);
#pragma unroll
    for (int mi = 0; mi < 8; ++mi) {
      acc[mi][0] = mfma16(af[mi], b0, acc[mi][0]);
      acc[mi][1] = mfma16(af[mi], b1, acc[mi][1]);
    }
    __builtin_amdgcn_s_setprio(0);
    asm volatile("" ::: "memory");
    __builtin_amdgcn_s_barrier();
    // ---- P1: read bf{2..} kh0 | stage B01(t+1)
#pragma unroll
    for (int j = 2; j < NJ; ++j) bx[j - 2] = *(const bf16x8*)(ldsB + j * 4096 + swz0);
    if (st) { stgB(kn, nsel, 0); stgB(kn, nsel, 1); }
    asm volatile("" ::: "memory");
    __builtin_amdgcn_s_barrier();
    asm volatile("s_waitcnt lgkmcnt(0)" ::: "memory");
    __builtin_amdgcn_sched_barrier(0);
    __builtin_amdgcn_s_setprio(1);
#pragma unroll
    for (int mi = 0; mi < 8; ++mi)
#pragma unroll
      for (int j = 2; j < NJ; ++j) acc[mi][j] = mfma16(af[mi], bx[j - 2], acc[mi][j]);
    __builtin_amdgcn_s_setprio(0);
    asm volatile("" ::: "memory");
    __builtin_amdgcn_s_barrier();
    // ---- P2: read af kh1 + bf{0,1} kh1 | stage B23(t+1)
#pragma unroll
    for (int mi = 0; mi < 8; ++mi) af[mi] = *(const bf16x8*)(ldsA + mi * 1024 + swz1);
    b0 = *(const bf16x8*)(ldsB + swz1);
    b1 = *(const bf16x8*)(ldsB + 4096 + swz1);
    if (st) { stgB(kn, nsel, 2); if constexpr (NJ == 5) stgB(kn, nsel, 3); }
    asm volatile("" ::: "memory");
    __builtin_amdgcn_s_barrier();
    asm volatile("s_waitcnt lgkmcnt(0)" ::: "memory");
    __builtin_amdgcn_sched_barrier(0);
    __builtin_amdgcn_s_setprio(1);
#pragma unroll
    for (int mi = 0; mi < 8; ++mi) {
      acc[mi][0] = mfma16(af[mi], b0, acc[mi][0]);
      acc[mi][1] = mfma16(af[mi], b1, acc[mi][1]);
    }
    __builtin_amdgcn_s_setprio(0);
    asm volatile("" ::: "memory");
    __builtin_amdgcn_s_barrier();
    // ---- P3: read bf{2..} kh1 | stage B4(t+1) | vmcnt(NJ-2) [A+B01 of t+1 land]
#pragma unroll
    for (int j = 2; j < NJ; ++j) bx[j - 2] = *(const bf16x8*)(ldsB + j * 4096 + swz1);
    if (st) {
      if constexpr (NJ == 5) stgB(kn, nsel, 4);
      asm volatile("" ::: "memory");
      if constexpr (NJ == 5) WAITV(3); else WAITV(1);
    }
    __builtin_amdgcn_s_barrier();
    asm volatile("s_waitcnt lgkmcnt(0)" ::: "memory");
    __builtin_amdgcn_sched_barrier(0);
    __builtin_amdgcn_s_setprio(1);
#pragma unroll
    for (int mi = 0; mi < 8; ++mi)
#pragma unroll
      for (int j = 2; j < NJ; ++j) acc[mi][j] = mfma16(af[mi], bx[j - 2], acc[mi][j]);
    __builtin_amdgcn_s_setprio(0);
    asm volatile("" ::: "memory");
    __builtin_amdgcn_s_barrier();
  }
  // ---- epilogue (nn = n0 + j*64 + wn*16 + l15)
#pragma unroll
  for (int i = 0; i < 8; ++i)
#pragma unroll
    for (int j = 0; j < NJ; ++j) {
      int nn = n0 + j * 64 + wn * 16 + l15;
      int mmb = m0 + wm * 128 + i * 16 + g * 4;
      if (mode == 1) {
#pragma unroll
        for (int r = 0; r < 4; ++r)
          ((float*)Cv)[(size_t)(mmb + r) * N + nn] = acc[i][j][r];
      } else if (mode == 0) {
#pragma unroll
        for (int r = 0; r < 4; ++r)
          ((u16*)Cv)[(size_t)(mmb + r) * N + nn] = f2b(acc[i][j][r]);
      } else if (mode == 2) {
        u16x4 pk;
#pragma unroll
        for (int r = 0; r < 4; ++r) pk[r] = f2b(acc[i][j][r]);
        *(u16x4*)((u16*)Cv + (size_t)nn * 2048 + (size_t)(mmb >> 11) * 2097152 + (mmb & 2047)) = pk;
      } else {                                 // mode 3: QKV concat routing
        if (nn < 3072) {
#pragma unroll
          for (int r = 0; r < 4; ++r)
            ((u16*)Cv)[(size_t)(mmb + r) * 3072 + nn] = f2b(acc[i][j][r]);
        } else if (nn < 4096) {
#pragma unroll
          for (int r = 0; r < 4; ++r)
            ((u16*)C2)[(size_t)(mmb + r) * 1024 + (nn - 3072)] = f2b(acc[i][j][r]);
        } else {
          int d = nn - 4096;
          u16x4 pk;
#pragma unroll
          for (int r = 0; r < 4; ++r) pk[r] = f2b(acc[i][j][r]);
          *(u16x4*)((u16*)C3 + (size_t)d * 2048 + (size_t)(mmb >> 11) * 2097152 + (mmb & 2047)) = pk;
        }
      }
    }
}

// merged QKV projection: B = concatenated [wq;wk;wv] (5120x3072, contiguous in ws).
__global__ __launch_bounds__(512, 1) void gemm_qkv(const u16* __restrict__ A,
                                                   const u16* __restrict__ Wcat,
                                                   u16* __restrict__ Cq,
                                                   u16* __restrict__ Ck, u16* __restrict__ Cv,
                                                   int K) {
  __shared__ __align__(16) u16 lds[73728];     // 144 KB
  int id = blockIdx.x;
  int s = (id & 7) * 32 + (id >> 3);           // XCD-chunked
  int by = s >> 4, c = s & 15;
  gemm256_body<320>(lds, A, Wcat, Cq, 0, K, by * 256, c * 320, 3, Ck, Cv);
}
// O-projection (f32 out), grid (16,16)
__global__ __launch_bounds__(512, 1) void gemm192_f32(const u16* __restrict__ A, const u16* __restrict__ B,
                                                      float* __restrict__ C, int N, int K) {
  __shared__ __align__(16) u16 lds[57344];
  int bx, by; swz_bid(bx, by);
  gemm256_body<192>(lds, A, B, C, N, K, by * 256, bx * 192, 1);
}

// ---------------- RoPE (in place, bf16) — K only ----------------
__global__ __launch_bounds__(256) void rope_kernel(u16* __restrict__ t, const float* __restrict__ fc,
                                                   const float* __restrict__ fs, int nheads, int total) {
  int idx = blockIdx.x * 256 + threadIdx.x;
  if (idx >= total) return;
  int c = idx & 7;
  int tmp = idx >> 3;
  int h = tmp % nheads;
  int row = tmp / nheads;
  int s = row & (S_LEN - 1);
  int d0 = c << 3;
  u16* base = t + (size_t)row * (nheads * 128) + h * 128;
  u16x8 lo = *(const u16x8*)(base + d0);
  u16x8 hi = *(const u16x8*)(base + 64 + d0);
  const float* cp = fc + s * 64 + d0;
  const float* sp = fs + s * 64 + d0;
  u16x8 olo, ohi;
#pragma unroll
  for (int j = 0; j < 8; ++j) {
    float cv = cp[j], sn = sp[j];
    float a = b2f(lo[j]), b = b2f(hi[j]);
    olo[j] = f2b(a * cv - b * sn);
    ohi[j] = f2b(b * cv + a * sn);
  }
  *(u16x8*)(base + d0) = olo;
  *(u16x8*)(base + 64 + d0) = ohi;
}

// ---------------- causal GQA flash attention — single-panel LPT blocks ----------------
// r14 structure + VALU cuts: cvtpk P-packing (u32x2 stores), per-lane partial
// lsum (cross-lane reduce once per panel, not per tile), tree-max, cvtpk epilogue.
__global__ __launch_bounds__(256, 2) void attn_kernel(const u16* __restrict__ xq,
                                                      const u16* __restrict__ xk,
                                                      const u16* __restrict__ xvT,
                                                      const float* __restrict__ fc,
                                                      const float* __restrict__ fs,
                                                      u16* __restrict__ o,
                                                      const float* __restrict__ wo,
                                                      u16* __restrict__ wob) {
  __shared__ __align__(16) u16 smem[40960];    // 80 KB: K dbuf 32K + V dbuf 32K + P 16K
  if (blockIdx.x >= 768) {                     // cvt(wo) backfill blocks
    int i = (blockIdx.x - 768) * 256 + threadIdx.x;   // 4608*256 = 1179648 exactly
    cvt_one(wo, wob, i);
    return;
  }
  const int tid = threadIdx.x;
  const int w = tid >> 6, lane = tid & 63;
  const int l15 = lane & 15, g = lane >> 4;
  const int id = blockIdx.x;
  const int xcd = id & 7, slot = id >> 3;      // slot in [0,96)
  const int grp = xcd + 8 * (slot / 48);       // (b,kvh) group, 0..15
  const int s48 = slot % 48;
  const int b = grp >> 3, kvh = grp & 7;
  const int qb = 15 - s48 / 3;                 // qb descending (LPT)
  const int h = kvh * 3 + s48 % 3;
  const float sc2 = 0.08838834764831845f * 1.4426950408889634f;  // 1/sqrt(128)*log2e

  const u16* ksrc = xk + (size_t)b * 2097152 + kvh * 128;          // [s][1024]
  const u16* vsrc = xvT + (size_t)(b * 1024 + kvh * 128) * 2048;   // [d][2048]
  int koff[4], vofs[4], dst4[4];
#pragma unroll
  for (int r = 0; r < 4; ++r) {
    int c = r * 256 + tid;
    int krow = c >> 4, kj = (c & 15) ^ (krow & 7);   // K: 64 rows x 16 chunks
    koff[r] = krow * 1024 + kj * 8;
    int vrow = c >> 3, vj = (c & 7) ^ (vrow & 7);    // V^T: 128 rows x 8 chunks
    vofs[r] = vrow * 2048 + vj * 8;
    dst4[r] = (r * 256 + (tid & 192)) * 8;           // wave-uniform LDS chunk base
  }
  u16* sPw = smem + 32768 + w * 2048;          // per-wave P: 2 sets x 1024 u16
  const int pxr = (l15 & 7) << 3;

  const int q0 = qb * 128;

  // Q load + fused RoPE + pre-scale, 2 sets
  bf16x8 qf[2][4];
#pragma unroll
  for (int s = 0; s < 2; ++s) {
    const int qrow = q0 + w * 32 + s * 16 + l15;
    const u16* qptr = xq + (size_t)(b * S_LEN + qrow) * DM + h * 128;
#pragma unroll
    for (int dcp = 0; dcp < 2; ++dcp) {
      u16x8 Lo = *(const u16x8*)(qptr + dcp * 32 + g * 8);
      u16x8 Hi = *(const u16x8*)(qptr + 64 + dcp * 32 + g * 8);
      const float* cp = fc + qrow * 64 + dcp * 32 + g * 8;
      const float* sp = fs + qrow * 64 + dcp * 32 + g * 8;
      bf16x8 qlo, qhi;
#pragma unroll
      for (int j = 0; j < 8; ++j) {
        float cv = cp[j], sn = sp[j];
        float a = b2f(Lo[j]), bb = b2f(Hi[j]);
        qlo[j] = (__bf16)((a * cv - bb * sn) * sc2);
        qhi[j] = (__bf16)((bb * cv + a * sn) * sc2);
      }
      qf[s][dcp] = qlo;
      qf[s][dcp + 2] = qhi;
    }
  }

  u16 *sKc = smem, *sKn = smem + 8192;
  u16 *sVc = smem + 16384, *sVn = smem + 24576;

  f32x4 accO[2][8];
#pragma unroll
  for (int s = 0; s < 2; ++s)
#pragma unroll
    for (int i = 0; i < 8; ++i) accO[s][i] = 0.f;
  float m_[2] = {-1e30f, -1e30f}, ls_[2] = {0.f, 0.f};
  const int nt = 2 * qb + 2;

#pragma unroll
  for (int r = 0; r < 4; ++r) gload16(ksrc + koff[r], sKc + dst4[r]);
#pragma unroll
  for (int r = 0; r < 4; ++r) gload16(vsrc + vofs[r], sVc + dst4[r]);
  __syncthreads();

  for (int t = 0; t < nt; ++t) {
    if (t + 1 < nt) {
      int k0n = (t + 1) * 64;
#pragma unroll
      for (int r = 0; r < 4; ++r) gload16(ksrc + (size_t)k0n * 1024 + koff[r], sKn + dst4[r]);
#pragma unroll
      for (int r = 0; r < 4; ++r) gload16(vsrc + k0n + vofs[r], sVn + dst4[r]);
    }
    if (64 * t <= q0 + w * 32 + 31) {           // wave-level causal skip
      f32x4 st[2][4];
      __builtin_amdgcn_s_setprio(1);
#pragma unroll
      for (int kt = 0; kt < 4; ++kt) {
        int row = kt * 16 + l15;
        bf16x8 kf[4];
#pragma unroll
        for (int dc = 0; dc < 4; ++dc)
          kf[dc] = *(const bf16x8*)(sKc + row * 128 + ((dc * 32 + g * 8) ^ ((row & 7) << 3)));
        f32x4 a0 = 0.f, a1 = 0.f;
#pragma unroll
        for (int dc = 0; dc < 4; ++dc) {
          a0 = mfma16(kf[dc], qf[0][dc], a0);
          a1 = mfma16(kf[dc], qf[1][dc], a1);
        }
        st[0][kt] = a0;
        st[1][kt] = a1;
      }
      __builtin_amdgcn_s_setprio(0);
      // softmax per set: mask, tree-max, defer-max, exp2, cvtpk pack, partial lsum
#pragma unroll
      for (int s = 0; s < 2; ++s) {
        const int qrow = q0 + w * 32 + s * 16 + l15;
#pragma unroll
        for (int kt = 0; kt < 4; ++kt)
#pragma unroll
          for (int r = 0; r < 4; ++r) {
            float x = st[s][kt][r];
            if (t >= nt - 2) {
              int kk = t * 64 + kt * 16 + g * 4 + r;
              if (kk > qrow) x = -1e30f;
            }
            st[s][kt][r] = x;
          }
        float pm0 = fmaxf(fmaxf(st[s][0][0], st[s][0][1]), fmaxf(st[s][0][2], st[s][0][3]));
        float pm1 = fmaxf(fmaxf(st[s][1][0], st[s][1][1]), fmaxf(st[s][1][2], st[s][1][3]));
        float pm2 = fmaxf(fmaxf(st[s][2][0], st[s][2][1]), fmaxf(st[s][2][2], st[s][2][3]));
        float pm3 = fmaxf(fmaxf(st[s][3][0], st[s][3][1]), fmaxf(st[s][3][2], st[s][3][3]));
        float pmax = fmaxf(fmaxf(pm0, pm1), fmaxf(pm2, pm3));
        pmax = fmaxf(pmax, __shfl_xor(pmax, 16));
        pmax = fmaxf(pmax, __shfl_xor(pmax, 32));
        if (!__all(pmax - m_[s] <= 8.0f)) {    // defer-max
          float mnew = fmaxf(m_[s], pmax);
          float corr = exp2f(m_[s] - mnew);
          ls_[s] *= corr;
#pragma unroll
          for (int i = 0; i < 8; ++i) accO[s][i] *= corr;
          m_[s] = mnew;
        }
        float ps = 0.f;
#pragma unroll
        for (int kt = 0; kt < 4; ++kt) {
          float p0 = exp2f(st[s][kt][0] - m_[s]);
          float p1 = exp2f(st[s][kt][1] - m_[s]);
          float p2 = exp2f(st[s][kt][2] - m_[s]);
          float p3 = exp2f(st[s][kt][3] - m_[s]);
          ps += (p0 + p1) + (p2 + p3);
          u32x2 pr;
          pr[0] = cvtpk(p0, p1);
          pr[1] = cvtpk(p2, p3);
          *(u32x2*)(sPw + s * 1024 + ((l15 * 64 + kt * 16 + g * 4) ^ pxr)) = pr;
        }
        ls_[s] += ps;                          // per-lane partial; reduce at epilogue
      }
      // P fragments (wave-local LDS)
      bf16x8 pf[2][2];
#pragma unroll
      for (int s = 0; s < 2; ++s)
#pragma unroll
        for (int ck = 0; ck < 2; ++ck)
          pf[s][ck] = *(const bf16x8*)(sPw + s * 1024 + ((l15 * 64 + ck * 32 + g * 8) ^ pxr));
      // PV both sets: each vf read feeds 2 MFMAs
      __builtin_amdgcn_s_setprio(1);
#pragma unroll
      for (int dt = 0; dt < 8; ++dt) {
        int row = dt * 16 + l15;
#pragma unroll
        for (int ck = 0; ck < 2; ++ck) {
          bf16x8 vf = *(const bf16x8*)(sVc + row * 64 + ((ck * 32 + g * 8) ^ ((row & 7) << 3)));
          accO[0][dt] = mfma16(vf, pf[0][ck], accO[0][dt]);
          accO[1][dt] = mfma16(vf, pf[1][ck], accO[1][dt]);
        }
      }
      __builtin_amdgcn_s_setprio(0);
    }
    __syncthreads();                            // drains stage vmcnt + cur reads done
    u16* tk = sKc; sKc = sKn; sKn = tk;
    u16* tv = sVc; sVc = sVn; sVn = tv;
  }
  // cross-lane lsum reduce (deferred from the k-loop)
#pragma unroll
  for (int s = 0; s < 2; ++s) {
    ls_[s] += __shfl_xor(ls_[s], 16);
    ls_[s] += __shfl_xor(ls_[s], 32);
  }
  // epilogue: per-wave [32 q][128 d] transpose in (dead) K/V LDS region
  u16* sOw = smem + w * 8192;
#pragma unroll
  for (int s = 0; s < 2; ++s) {
    float invl = 1.0f / ls_[s];
#pragma unroll
    for (int dt = 0; dt < 8; ++dt) {
      u32x2 pr;
      pr[0] = cvtpk(accO[s][dt][0] * invl, accO[s][dt][1] * invl);
      pr[1] = cvtpk(accO[s][dt][2] * invl, accO[s][dt][3] * invl);
      int d = dt * 16 + g * 4;
      *(u32x2*)(sOw + (((s * 16 + l15) * 128 + d) ^ pxr)) = pr;
    }
  }
#pragma unroll
  for (int p = 0; p < 8; ++p) {
    int idx = p * 64 + lane;
    int q = idx >> 4, c = idx & 15;
    int j = c ^ (q & 7);
    u32x4 v = *(const u32x4*)(sOw + q * 128 + j * 8);
    *(u32x4*)(o + (size_t)(b * S_LEN + q0 + w * 32 + q) * DM + h * 128 + c * 8) = v;
  }
}

// ---------------- launch ----------------
extern "C" void kernel_launch(void* const* d_in, const int* in_sizes, int n_in,
                              void* d_out, int out_size, void* d_ws, size_t ws_size,
                              hipStream_t stream) {
  const float* x  = (const float*)d_in[0];
  const float* fc = (const float*)d_in[1];
  const float* fs = (const float*)d_in[2];
  const float* wq = (const float*)d_in[4];
  const float* wk = (const float*)d_in[5];
  const float* wv = (const float*)d_in[6];
  const float* wo = (const float*)d_in[7];
  float* out = (float*)d_out;
  char* ws = (char*)d_ws;

  u16* xb  = (u16*)(ws);                 // x bf16      25,165,824
  u16* wqb = (u16*)(ws + 25165824);      // wq bf16     18,874,368 ┐ contiguous = Wcat
  u16* att = (u16*)(ws + 25165824);      // attn out (aliases wq/wk after death)
  u16* wkb = (u16*)(ws + 44040192);      // wk bf16      6,291,456 │ (5120 x 3072)
  u16* wvb = (u16*)(ws + 50331648);      // wv bf16      6,291,456 ┘
  u16* xqb = (u16*)(ws + 56623104);      // xq bf16     25,165,824
  u16* xkb = (u16*)(ws + 81788928);      // xk bf16      8,388,608
  u16* xvT = (u16*)(ws + 90177536);      // V^T bf16     8,388,608
  u16* wob = (u16*)(ws);                 // wo bf16 (aliases xb, dead after gemm_qkv)

  cvt4_kernel<<<13824, 256, 0, stream>>>(x, xb, wq, wqb, wk, wkb, wv, wvb);

  gemm_qkv<<<256, 512, 0, stream>>>(xb, wqb, xqb, xkb, xvT, 3072);

  rope_kernel<<<1024, 256, 0, stream>>>(xkb, fc, fs, NKV, 4096 * NKV * 8);  // K only

  attn_kernel<<<5376, 256, 0, stream>>>(xqb, xkb, xvT, fc, fs, att, wo, wob);

  gemm192_f32<<<dim3(16, 16), 512, 0, stream>>>(att, wob, out, 3072, 3072);
}